// Round 3
// baseline (437.864 us; speedup 1.0000x reference)
//
#include <hip/hip_runtime.h>
#include <math.h>

#define NPTS 262144
#define MT 64          // points per block

typedef __attribute__((ext_vector_type(8))) short bf16x8;
typedef __attribute__((ext_vector_type(4))) float f32x4;
typedef __attribute__((ext_vector_type(16))) float f32x16;
typedef __attribute__((ext_vector_type(2))) unsigned int u32x2;

#if defined(__has_builtin)
#if __has_builtin(__builtin_amdgcn_cvt_pk_bf16_f32)
#define HAVE_CVT_PK_BF16 1
#endif
#endif

__device__ __forceinline__ short f2bf(float f) {
    union { float f; unsigned u; } v; v.f = f;
    unsigned r = v.u + 0x7fffu + ((v.u >> 16) & 1u);   // RNE
    return (short)(r >> 16);
}
__device__ __forceinline__ unsigned pk2(float a, float b) {
#ifdef HAVE_CVT_PK_BF16
    auto r = __builtin_amdgcn_cvt_pk_bf16_f32(a, b);   // 1 instr, RNE
    unsigned u; __builtin_memcpy(&u, &r, 4);
    return u;
#else
    return ((unsigned)(unsigned short)f2bf(a)) |
           ((unsigned)(unsigned short)f2bf(b) << 16);
#endif
}

// ---- swizzled-weight workspace layout (offsets in bf16 elements) ----
// All big layers in 32x32x16 fragment format; density + r2 keep 16x16x32.
#define OFF_IN   0
#define SZ_IN    (64*256)
#define OFF_H0   (OFF_IN + SZ_IN)
#define SZ_H     (256*256)
#define OFF_H1   (OFF_H0 + SZ_H)
#define OFF_H2   (OFF_H1 + SZ_H)
#define OFF_H3   (OFF_H2 + SZ_H)
#define OFF_H4   (OFF_H3 + SZ_H)
#define SZ_H4    (320*256)
#define OFF_H5   (OFF_H4 + SZ_H4)
#define OFF_H6   (OFF_H5 + SZ_H)
#define OFF_OUT  (OFF_H6 + SZ_H)
#define SZ_OUTM  (256*256)          // out features, 32-fmt
#define OFF_OUTD (OFF_OUT + SZ_OUTM)
#define SZ_OUTD  (256*16)           // density column, 16-fmt (n=0 real)
#define OFF_R1   (OFF_OUTD + SZ_OUTD)
#define SZ_R1    (288*128)
#define OFF_R2   (OFF_R1 + SZ_R1)
#define SZ_R2    (128*16)
#define WS_TOTAL (OFF_R2 + SZ_R2)

// ---------------- weight prep: f32 -> bf16, fragment swizzle ----------------
// 32-fmt tile (kt,nb): elem ((kt*nNb + nb)*64 + L)*8 + j
//   holds W[kt*16 + (L>>5)*8 + j][nb*32 + (L&31)]  (0-padded)
//   -> A operand of A=W^T: A[n=lane&31][k=(lane>>5)*8+j].
// 16-fmt tile (kt,nt): elem ((kt*nNt + nt)*64 + L)*8 + j
//   holds W[kt*32 + (L>>4)*8 + j][nt*16 + (L&15)].
struct PrepP { const float* W[11]; short* ws; };

__global__ __launch_bounds__(256) void prep_all(PrepP pp) {
    int i = blockIdx.x * 256 + threadIdx.x;
    if (i >= WS_TOTAL) return;
    const int offs[13] = {OFF_IN, OFF_H0, OFF_H1, OFF_H2, OFF_H3, OFF_H4,
                          OFF_H5, OFF_H6, OFF_OUT, OFF_OUTD, OFF_R1, OFF_R2,
                          WS_TOTAL};
    const int wsrc[12] = {0,1,2,3,4,5,6,7,8,8,9,10};
    const int Ks[12]   = {63,256,256,256,256,319,256,256,256,256,283,128};
    const int Nsrc[12] = {256,256,256,256,256,256,256,256,257,257,128,3};
    int seg = 0;
    while (i >= offs[seg + 1]) seg++;
    int li = i - offs[seg];
    int j = li & 7, L = (li >> 3) & 63, tile = li >> 9;
    const float* W = pp.W[wsrc[seg]];
    float v = 0.f;
    if (seg == 9) {                        // density: 16-fmt, frag n==0 <- col 256
        int k = tile * 32 + ((L >> 4) << 3) + j;
        if (k < 256 && (L & 15) == 0) v = W[k * 257 + 256];
    } else if (seg == 11) {                // r2: 16-fmt, N=3
        int k = tile * 32 + ((L >> 4) << 3) + j;
        int n = L & 15;
        if (k < 128 && n < 3) v = W[k * 3 + n];
    } else {                               // 32-fmt
        int nNb = (seg == 10) ? 4 : 8;
        int nb = tile % nNb, kt = tile / nNb;
        int k = kt * 16 + ((L >> 5) << 3) + j;
        int n = nb * 32 + (L & 31);
        if (k < Ks[seg]) v = W[k * Nsrc[seg] + n];
    }
    pp.ws[i] = f2bf(v);
}

// ---------------- fused MLP ----------------
struct Params {
    const float *pos, *dir;
    const float *b_in, *b_h0, *b_h1, *b_h2, *b_h3, *b_h4, *b_h5, *b_h6;
    const float *b_out, *b_r1, *b_r2;
    const short *w;
    float *out;
};

// X LDS: ping-pong pair, k-grouped B-fragment layout (element (k,m) of
// activation X[m][k] at short index ((k>>3)*64 + m)*8 + (k&7)).
//  - shape-agnostic: serves 32x32x16 (K-halves of 8+8) and 16x16x32
//    (K-quads of 8) reads, all conflict-free b128, base VGPR + immediate.
//  - XA = 32 k-groups (256 cols), XB = 40 (320 cols: pe-skip/de in 32..39).
//
// Single barrier per layer: [issue a(kt=0,1) global prefetch] BARRIER
// [K-loop reads Xin] [epilogue writes Xout]. In-loop a-prefetch dist-2
// (L2 ~200-400cy), b-prefetch dist-1 (LDS ~120cy).
// 32x32x16 MFMA: A = W^T (32 n x 16 k), B = X^T (16 k x 32 m).
// C (verified m74/m101): col(m)=lane&31, row(n)=(reg&3)+8*(reg>>2)+4*(lane>>5).
// MODE 0: relu -> Xout. MODE 1: features (no relu) -> Xout; density row via
// 16x16 pre-pass (waves 0..3, OFF_OUTD region) straight to gmem.
template<int NKT, int NNB, int TM, int MODE>
__device__ __forceinline__ void layer32(const short* __restrict__ Wsw,
                                        const short* __restrict__ Wd,
                                        const float* __restrict__ bias,
                                        const short* Xin, short* Xout,
                                        float* dout, int p0,
                                        int nb, int mbB, int wave, int lane) {
    const int l31 = lane & 31, hi = lane >> 5;
    const short* xb = Xin + hi * 512 + l31 * 8 + mbB * 256;  // + t*256 + kt*1024
    const short* wp = Wsw + (size_t)(nb * 64 + lane) * 8;    // + kt*NNB*512

    // pre-barrier: first two k-tiles of weights (global; latency overlaps
    // barrier arrival, drained by the barrier's vmcnt wait)
    bf16x8 a0 = *(const bf16x8*)(wp);
    bf16x8 a1 = *(const bf16x8*)(wp + (size_t)NNB * 512);

    __syncthreads();                      // Xin ready; Xout free to overwrite

    if (MODE == 1 && wave < 4) {          // density pre-pass (16-fmt region)
        const int l15 = lane & 15, quad = lane >> 4;
        const short* xd = Xin + quad * 512 + (wave * 16 + l15) * 8;
        f32x4 ad = (f32x4){0.f, 0.f, 0.f, 0.f};
#pragma unroll
        for (int kt = 0; kt < 8; ++kt) {
            bf16x8 b = *(const bf16x8*)(xd + kt * 2048);
            bf16x8 a = *(const bf16x8*)(Wd + (size_t)(kt * 64 + lane) * 8);
            ad = __builtin_amdgcn_mfma_f32_16x16x32_bf16(a, b, ad, 0, 0, 0);
        }
        if (quad == 0)                    // C row 0 = n 256 (density)
            dout[3 * NPTS + p0 + wave * 16 + l15] = fmaxf(ad[0] + bias[256], 0.f);
    }

    f32x16 acc[TM];
#pragma unroll
    for (int t = 0; t < TM; t++)
#pragma unroll
        for (int r = 0; r < 16; r++) acc[t][r] = 0.f;

    bf16x8 b_c[TM];
#pragma unroll
    for (int t = 0; t < TM; t++)
        b_c[t] = *(const bf16x8*)(xb + t * 256);

#pragma unroll
    for (int kt = 0; kt < NKT; ++kt) {
        bf16x8 b_n[TM], a_n;
        if (kt + 1 < NKT) {
#pragma unroll
            for (int t = 0; t < TM; t++)
                b_n[t] = *(const bf16x8*)(xb + (kt + 1) * 1024 + t * 256);
        }
        if (kt + 2 < NKT)
            a_n = *(const bf16x8*)(wp + (size_t)(kt + 2) * NNB * 512);
        if ((kt & 1) == 0) {
#pragma unroll
            for (int t = 0; t < TM; t++)
                acc[t] = __builtin_amdgcn_mfma_f32_32x32x16_bf16(a0, b_c[t], acc[t], 0, 0, 0);
        } else {
#pragma unroll
            for (int t = 0; t < TM; t++)
                acc[t] = __builtin_amdgcn_mfma_f32_32x32x16_bf16(a1, b_c[t], acc[t], 0, 0, 0);
        }
        if (kt + 2 < NKT) {
            if ((kt & 1) == 0) a0 = a_n; else a1 = a_n;
        }
        if (kt + 1 < NKT) {
#pragma unroll
            for (int t = 0; t < TM; t++) b_c[t] = b_n[t];
        }
    }

    // epilogue -> Xout (Xout reads closed by entry barrier; next layer's
    // entry barrier publishes these writes). n = 32nb + 8rq + 4hi + r.
#pragma unroll
    for (int t = 0; t < TM; t++) {
        const int m = (mbB + t) * 32 + l31;
#pragma unroll
        for (int rq = 0; rq < 4; rq++) {
            const int nbase = nb * 32 + rq * 8 + hi * 4;
            const f32x4 bv = *(const f32x4*)(bias + nbase);
            float v0 = acc[t][rq * 4 + 0] + bv[0];
            float v1 = acc[t][rq * 4 + 1] + bv[1];
            float v2 = acc[t][rq * 4 + 2] + bv[2];
            float v3 = acc[t][rq * 4 + 3] + bv[3];
            if (MODE == 0) {
                v0 = fmaxf(v0, 0.f); v1 = fmaxf(v1, 0.f);
                v2 = fmaxf(v2, 0.f); v3 = fmaxf(v3, 0.f);
            }
            u32x2 w; w[0] = pk2(v0, v1); w[1] = pk2(v2, v3);
            *(u32x2*)(Xout + ((size_t)(nb * 4 + rq) * 64 + m) * 8 + hi * 4) = w;
        }
    }
}

__global__ __launch_bounds__(512, 4) void nerf_fused(Params P) {
    __shared__ __align__(16) short XA[32 * 512];   // 32 KB (256 cols)
    __shared__ __align__(16) short XB[40 * 512];   // 40 KB (320 cols)
    const int tid = threadIdx.x;
    const int wave = tid >> 6, lane = tid & 63;
    const int p0 = blockIdx.x * MT;

    // ---- positional encoding: lane owns one (pt, k-group) -> 8 cols,
    //      packed b128 stores (conflict-free; g wave-uniform branches) ----
    {
        const int pt = tid & 63, g = tid >> 6;    // g = 0..7
        const float x0 = P.pos[(p0 + pt) * 3 + 0];
        const float x1 = P.pos[(p0 + pt) * 3 + 1];
        const float x2 = P.pos[(p0 + pt) * 3 + 2];
        bf16x8 v;
#pragma unroll
        for (int j = 0; j < 8; j++) {
            const int d = g * 8 + j;
            float val = 0.f;
            if (d < 3) val = (d == 0) ? x0 : (d == 1) ? x1 : x2;
            else if (d < 63) {
                const int e = d - 3, f = e / 6, r = e % 6;
                const float x = (r % 3 == 0) ? x0 : (r % 3 == 1) ? x1 : x2;
                const float xf = x * (float)(1 << f);
                val = (r < 3) ? sinf(xf) : cosf(xf);
            }
            v[j] = f2bf(val);
        }
        *(bf16x8*)(XA + ((size_t)g * 64 + pt) * 8) = v;          // input cols
        *(bf16x8*)(XB + ((size_t)(32 + g) * 64 + pt) * 8) = v;   // h4 skip copy
    }

    // ---- dir encoding into registers (waves 0..3); spliced into XB
    //      groups 32..35 once h4's reads are closed ----
    bf16x8 de_v;
    if (wave < 4) {
        const int pt = tid & 63, g = wave;        // cols 8g..8g+7
        const float x0 = P.dir[(p0 + pt) * 3 + 0];
        const float x1 = P.dir[(p0 + pt) * 3 + 1];
        const float x2 = P.dir[(p0 + pt) * 3 + 2];
#pragma unroll
        for (int j = 0; j < 8; j++) {
            const int d = g * 8 + j;
            float val = 0.f;
            if (d < 3) val = (d == 0) ? x0 : (d == 1) ? x1 : x2;
            else if (d < 27) {
                const int e = d - 3, f = e / 6, r = e % 6;
                const float x = (r % 3 == 0) ? x0 : (r % 3 == 1) ? x1 : x2;
                const float xf = x * (float)(1 << f);
                val = (r < 3) ? sinf(xf) : cosf(xf);
            }
            de_v[j] = f2bf(val);
        }
    }

    // hidden/out: 8 waves, each nb = wave (32 n), both m-blocks (64 pts)
    layer32< 4, 8, 2, 0>(P.w + OFF_IN, nullptr, P.b_in, XA, XB, P.out, p0, wave, 0, wave, lane);
    layer32<16, 8, 2, 0>(P.w + OFF_H0, nullptr, P.b_h0, XB, XA, P.out, p0, wave, 0, wave, lane);
    layer32<16, 8, 2, 0>(P.w + OFF_H1, nullptr, P.b_h1, XA, XB, P.out, p0, wave, 0, wave, lane);
    layer32<16, 8, 2, 0>(P.w + OFF_H2, nullptr, P.b_h2, XB, XA, P.out, p0, wave, 0, wave, lane);
    layer32<16, 8, 2, 0>(P.w + OFF_H3, nullptr, P.b_h3, XA, XB, P.out, p0, wave, 0, wave, lane);
    layer32<20, 8, 2, 0>(P.w + OFF_H4, nullptr, P.b_h4, XB, XA, P.out, p0, wave, 0, wave, lane); // concat
    layer32<16, 8, 2, 0>(P.w + OFF_H5, nullptr, P.b_h5, XA, XB, P.out, p0, wave, 0, wave, lane);

    // DE splice into XB groups 32..35: h5's entry barrier closed h4's reads
    // of XB[32..39]; h5/out write only XB[0..31]; r1's entry barrier
    // publishes these writes. Cols 283..287 are real zeros.
    if (wave < 4)
        *(bf16x8*)(XB + ((size_t)(32 + wave) * 64 + (tid & 63)) * 8) = de_v;

    layer32<16, 8, 2, 0>(P.w + OFF_H6, nullptr, P.b_h6, XB, XA, P.out, p0, wave, 0, wave, lane);
    layer32<16, 8, 2, 1>(P.w + OFF_OUT, P.w + OFF_OUTD, P.b_out, XA, XB, P.out, p0, wave, 0, wave, lane);

    // r1 (K=288 -> 128): 4 n-blocks x 2 m-blocks over 8 waves
    layer32<18, 4, 1, 0>(P.w + OFF_R1, nullptr, P.b_r1, XB, XA, P.out, p0, wave & 3, wave >> 2, wave, lane);

    // ---- r2 (128 -> 3) + sigmoid; 16x16, waves 0..3 one 16-pt tile each ----
    __syncthreads();
    if (wave < 4) {
        const int l15 = lane & 15, quad = lane >> 4;
        f32x4 acc = (f32x4){0.f, 0.f, 0.f, 0.f};
        const short* xb = XA + quad * 512 + (wave * 16 + l15) * 8;
#pragma unroll
        for (int kt = 0; kt < 4; ++kt) {
            bf16x8 b = *(const bf16x8*)(xb + kt * 2048);
            bf16x8 a = *(const bf16x8*)(P.w + OFF_R2 + (size_t)(kt * 64 + lane) * 8);
            acc = __builtin_amdgcn_mfma_f32_16x16x32_bf16(a, b, acc, 0, 0, 0);
        }
        if (quad == 0) {                   // rows r = rgb channel
#pragma unroll
            for (int r = 0; r < 3; r++) {
                const float v = acc[r] + P.b_r2[r];
                P.out[(size_t)(p0 + wave * 16 + l15) * 3 + r] = 1.f / (1.f + expf(-v));
            }
        }
    }
}

extern "C" void kernel_launch(void* const* d_in, const int* in_sizes, int n_in,
                              void* d_out, int out_size, void* d_ws, size_t ws_size,
                              hipStream_t stream) {
    short* ws = (short*)d_ws;

    PrepP pp;
    pp.W[0]  = (const float*)d_in[2];   // W_in
    pp.W[1]  = (const float*)d_in[4];   // W_h0
    pp.W[2]  = (const float*)d_in[6];   // W_h1
    pp.W[3]  = (const float*)d_in[8];   // W_h2
    pp.W[4]  = (const float*)d_in[10];  // W_h3
    pp.W[5]  = (const float*)d_in[12];  // W_h4
    pp.W[6]  = (const float*)d_in[14];  // W_h5
    pp.W[7]  = (const float*)d_in[16];  // W_h6
    pp.W[8]  = (const float*)d_in[18];  // W_out
    pp.W[9]  = (const float*)d_in[20];  // W_r1
    pp.W[10] = (const float*)d_in[22];  // W_r2
    pp.ws = ws;
    hipLaunchKernelGGL(prep_all, dim3((WS_TOTAL + 255) / 256), dim3(256), 0, stream, pp);

    Params P;
    P.pos  = (const float*)d_in[0];
    P.dir  = (const float*)d_in[1];
    P.b_in = (const float*)d_in[3];
    P.b_h0 = (const float*)d_in[5];
    P.b_h1 = (const float*)d_in[7];
    P.b_h2 = (const float*)d_in[9];
    P.b_h3 = (const float*)d_in[11];
    P.b_h4 = (const float*)d_in[13];
    P.b_h5 = (const float*)d_in[15];
    P.b_h6 = (const float*)d_in[17];
    P.b_out = (const float*)d_in[19];
    P.b_r1 = (const float*)d_in[21];
    P.b_r2 = (const float*)d_in[23];
    P.w = ws;
    P.out = (float*)d_out;
    hipLaunchKernelGGL(nerf_fused, dim3(NPTS / MT), dim3(512), 0, stream, P);
}

// Round 4
// 402.639 us; speedup vs baseline: 1.0875x; 1.0875x over previous
//
#include <hip/hip_runtime.h>
#include <math.h>

#define NPTS 262144
#define MT 128         // points per block

typedef __attribute__((ext_vector_type(8))) short bf16x8;
typedef __attribute__((ext_vector_type(4))) float f32x4;
typedef __attribute__((ext_vector_type(16))) float f32x16;
typedef __attribute__((ext_vector_type(2))) unsigned int u32x2;

#if defined(__has_builtin)
#if __has_builtin(__builtin_amdgcn_cvt_pk_bf16_f32)
#define HAVE_CVT_PK_BF16 1
#endif
#endif

__device__ __forceinline__ short f2bf(float f) {
    union { float f; unsigned u; } v; v.f = f;
    unsigned r = v.u + 0x7fffu + ((v.u >> 16) & 1u);   // RNE
    return (short)(r >> 16);
}
__device__ __forceinline__ unsigned pk2(float a, float b) {
#ifdef HAVE_CVT_PK_BF16
    auto r = __builtin_amdgcn_cvt_pk_bf16_f32(a, b);   // 1 instr, RNE
    unsigned u; __builtin_memcpy(&u, &r, 4);
    return u;
#else
    return ((unsigned)(unsigned short)f2bf(a)) |
           ((unsigned)(unsigned short)f2bf(b) << 16);
#endif
}

// ---- swizzled-weight workspace layout (offsets in bf16 elements) ----
// All big layers in 32x32x16 fragment format; density + r2 keep 16x16x32.
#define OFF_IN   0
#define SZ_IN    (64*256)
#define OFF_H0   (OFF_IN + SZ_IN)
#define SZ_H     (256*256)
#define OFF_H1   (OFF_H0 + SZ_H)
#define OFF_H2   (OFF_H1 + SZ_H)
#define OFF_H3   (OFF_H2 + SZ_H)
#define OFF_H4   (OFF_H3 + SZ_H)
#define SZ_H4    (320*256)
#define OFF_H5   (OFF_H4 + SZ_H4)
#define OFF_H6   (OFF_H5 + SZ_H)
#define OFF_OUT  (OFF_H6 + SZ_H)
#define SZ_OUTM  (256*256)          // out features, 32-fmt
#define OFF_OUTD (OFF_OUT + SZ_OUTM)
#define SZ_OUTD  (256*16)           // density column, 16-fmt (n=0 real)
#define OFF_R1   (OFF_OUTD + SZ_OUTD)
#define SZ_R1    (288*128)
#define OFF_R2   (OFF_R1 + SZ_R1)
#define SZ_R2    (128*16)
#define WS_TOTAL (OFF_R2 + SZ_R2)

// ---------------- weight prep: f32 -> bf16, fragment swizzle ----------------
// 32-fmt tile (kt,nb): elem ((kt*nNb + nb)*64 + L)*8 + j
//   holds W[kt*16 + (L>>5)*8 + j][nb*32 + (L&31)]  (0-padded)
//   -> A operand of A=W^T: A[n=lane&31][k=(lane>>5)*8+j].
// 16-fmt tile (kt,nt): elem ((kt*nNt + nt)*64 + L)*8 + j
//   holds W[kt*32 + (L>>4)*8 + j][nt*16 + (L&15)].
struct PrepP { const float* W[11]; short* ws; };

__global__ __launch_bounds__(256) void prep_all(PrepP pp) {
    int i = blockIdx.x * 256 + threadIdx.x;
    if (i >= WS_TOTAL) return;
    const int offs[13] = {OFF_IN, OFF_H0, OFF_H1, OFF_H2, OFF_H3, OFF_H4,
                          OFF_H5, OFF_H6, OFF_OUT, OFF_OUTD, OFF_R1, OFF_R2,
                          WS_TOTAL};
    const int wsrc[12] = {0,1,2,3,4,5,6,7,8,8,9,10};
    const int Ks[12]   = {63,256,256,256,256,319,256,256,256,256,283,128};
    const int Nsrc[12] = {256,256,256,256,256,256,256,256,257,257,128,3};
    int seg = 0;
    while (i >= offs[seg + 1]) seg++;
    int li = i - offs[seg];
    int j = li & 7, L = (li >> 3) & 63, tile = li >> 9;
    const float* W = pp.W[wsrc[seg]];
    float v = 0.f;
    if (seg == 9) {                        // density: 16-fmt, frag n==0 <- col 256
        int k = tile * 32 + ((L >> 4) << 3) + j;
        if (k < 256 && (L & 15) == 0) v = W[k * 257 + 256];
    } else if (seg == 11) {                // r2: 16-fmt, N=3
        int k = tile * 32 + ((L >> 4) << 3) + j;
        int n = L & 15;
        if (k < 128 && n < 3) v = W[k * 3 + n];
    } else {                               // 32-fmt
        int nNb = (seg == 10) ? 4 : 8;
        int nb = tile % nNb, kt = tile / nNb;
        int k = kt * 16 + ((L >> 5) << 3) + j;
        int n = nb * 32 + (L & 31);
        if (k < Ks[seg]) v = W[k * Nsrc[seg] + n];
    }
    pp.ws[i] = f2bf(v);
}

// ---------------- fused MLP ----------------
struct Params {
    const float *pos, *dir;
    const float *b_in, *b_h0, *b_h1, *b_h2, *b_h3, *b_h4, *b_h5, *b_h6;
    const float *b_out, *b_r1, *b_r2;
    const short *w;
    float *out;
};

// X LDS: single in-place buffer, MT=128 points. k-grouped B-fragment layout:
// element (k,m) of activation X[m][k] at short index ((k>>3)*128 + m)*8 + (k&7).
// 40 groups x 128 pts x 16B = 81920 B exact -> 2 blocks/CU at 512 thr.
// Groups 0..31 = 256 activation cols; 32..39 = PE skip copy, later DE.
//
// In-place layer: [issue a(kt=0,1) global prefetch] BAR1 (inputs published)
// [K-loop reads X] BAR2 (reads done) [epilogue writes X in place].
// MT=128 halves weight L2 traffic vs MT=64 (each weight frag serves 128 pts):
// ~2.4 GB/dispatch ~ 70 us at L2 ceiling, vs MFMA floor ~127 us.
// 32x32x16 MFMA: A = W^T (32 n x 16 k), B = X^T (16 k x 32 m).
// C (verified m74/m101): col(m)=lane&31, row(n)=(reg&3)+8*(reg>>2)+4*(lane>>5).
// Per wave: 1 n-block (nb) x TM m-blocks; 4 MFMA/kt. a-prefetch dist-2,
// b-prefetch dist-1.
// MODE 0: relu. MODE 1: out layer: features (no relu); density row via 16x16
// pre-pass (all 8 waves, m-tile = wave, OFF_OUTD region) straight to gmem.
template<int NKT, int NNB, int TM, int MODE>
__device__ __forceinline__ void layer32(const short* __restrict__ Wsw,
                                        const short* __restrict__ Wd,
                                        const float* __restrict__ bias,
                                        short* X, float* dout, int p0,
                                        int nb, int mbB, int wave, int lane) {
    const int l31 = lane & 31, hi = lane >> 5;
    const short* xb = X + hi * 1024 + (mbB * 32 + l31) * 8;  // + t*256 + kt*2048
    const short* wp = Wsw + (size_t)(nb * 64 + lane) * 8;    // + kt*NNB*512

    // pre-barrier: first two k-tiles of weights (global; latency overlaps
    // barrier arrival, drained by the barrier's vmcnt wait)
    bf16x8 a0 = *(const bf16x8*)(wp);
    bf16x8 a1 = *(const bf16x8*)(wp + (size_t)NNB * 512);

    __syncthreads();                      // BAR1: X inputs published

    if (MODE == 1) {                      // density pre-pass (16-fmt region)
        const int l15 = lane & 15, quad = lane >> 4;
        const short* xd = X + quad * 1024 + (wave * 16 + l15) * 8;
        f32x4 ad = (f32x4){0.f, 0.f, 0.f, 0.f};
#pragma unroll
        for (int kt = 0; kt < 8; ++kt) {
            bf16x8 b = *(const bf16x8*)(xd + kt * 4096);
            bf16x8 a = *(const bf16x8*)(Wd + (size_t)(kt * 64 + lane) * 8);
            ad = __builtin_amdgcn_mfma_f32_16x16x32_bf16(a, b, ad, 0, 0, 0);
        }
        if (quad == 0)                    // C row 0 = n 256 (density)
            dout[3 * NPTS + p0 + wave * 16 + l15] = fmaxf(ad[0] + bias[256], 0.f);
    }

    f32x16 acc[TM];
#pragma unroll
    for (int t = 0; t < TM; t++)
#pragma unroll
        for (int r = 0; r < 16; r++) acc[t][r] = 0.f;

    bf16x8 b_c[TM];
#pragma unroll
    for (int t = 0; t < TM; t++)
        b_c[t] = *(const bf16x8*)(xb + t * 256);

#pragma unroll
    for (int kt = 0; kt < NKT; ++kt) {
        bf16x8 b_n[TM], a_n;
        if (kt + 1 < NKT) {
#pragma unroll
            for (int t = 0; t < TM; t++)
                b_n[t] = *(const bf16x8*)(xb + (kt + 1) * 2048 + t * 256);
        }
        if (kt + 2 < NKT)
            a_n = *(const bf16x8*)(wp + (size_t)(kt + 2) * NNB * 512);
        if ((kt & 1) == 0) {
#pragma unroll
            for (int t = 0; t < TM; t++)
                acc[t] = __builtin_amdgcn_mfma_f32_32x32x16_bf16(a0, b_c[t], acc[t], 0, 0, 0);
        } else {
#pragma unroll
            for (int t = 0; t < TM; t++)
                acc[t] = __builtin_amdgcn_mfma_f32_32x32x16_bf16(a1, b_c[t], acc[t], 0, 0, 0);
        }
        if (kt + 2 < NKT) {
            if ((kt & 1) == 0) a0 = a_n; else a1 = a_n;
        }
        if (kt + 1 < NKT) {
#pragma unroll
            for (int t = 0; t < TM; t++) b_c[t] = b_n[t];
        }
    }

    __syncthreads();                      // BAR2: all reads of X done

    // epilogue -> X in place. n = 32nb + 8rq + 4hi + r.
#pragma unroll
    for (int t = 0; t < TM; t++) {
        const int m = (mbB + t) * 32 + l31;
#pragma unroll
        for (int rq = 0; rq < 4; rq++) {
            const int nbase = nb * 32 + rq * 8 + hi * 4;
            const f32x4 bv = *(const f32x4*)(bias + nbase);
            float v0 = acc[t][rq * 4 + 0] + bv[0];
            float v1 = acc[t][rq * 4 + 1] + bv[1];
            float v2 = acc[t][rq * 4 + 2] + bv[2];
            float v3 = acc[t][rq * 4 + 3] + bv[3];
            if (MODE == 0) {
                v0 = fmaxf(v0, 0.f); v1 = fmaxf(v1, 0.f);
                v2 = fmaxf(v2, 0.f); v3 = fmaxf(v3, 0.f);
            }
            u32x2 w; w[0] = pk2(v0, v1); w[1] = pk2(v2, v3);
            *(u32x2*)(X + (size_t)(nb * 4 + rq) * 1024 + m * 8 + hi * 4) = w;
        }
    }
}

__global__ __launch_bounds__(512, 4) void nerf_fused(Params P) {
    __shared__ __align__(16) short X[40 * 1024];   // 81920 B exact
    const int tid = threadIdx.x;
    const int wave = tid >> 6, lane = tid & 63;
    const int p0 = blockIdx.x * MT;

    // ---- positional encoding: item = (pt, k-group) -> 8 cols, b128 stores ----
    for (int i = tid; i < 128 * 8; i += 512) {
        const int pt = i & 127, g = i >> 7;       // g = 0..7
        const float x0 = P.pos[(p0 + pt) * 3 + 0];
        const float x1 = P.pos[(p0 + pt) * 3 + 1];
        const float x2 = P.pos[(p0 + pt) * 3 + 2];
        bf16x8 v;
#pragma unroll
        for (int j = 0; j < 8; j++) {
            const int d = g * 8 + j;
            float val = 0.f;
            if (d < 3) val = (d == 0) ? x0 : (d == 1) ? x1 : x2;
            else if (d < 63) {
                const int e = d - 3, f = e / 6, r = e % 6;
                const float x = (r % 3 == 0) ? x0 : (r % 3 == 1) ? x1 : x2;
                const float xf = x * (float)(1 << f);
                val = (r < 3) ? sinf(xf) : cosf(xf);
            }
            v[j] = f2bf(val);
        }
        *(bf16x8*)(X + ((size_t)g * 128 + pt) * 8) = v;          // input cols
        *(bf16x8*)(X + ((size_t)(32 + g) * 128 + pt) * 8) = v;   // h4 skip copy
    }

    // ---- dir encoding into registers (1 group per thread: 128 pts x 4 grp);
    //      spliced into groups 32..35 once h4's reads are closed ----
    bf16x8 de_v;
    const int ptD = tid & 127, gD = tid >> 7;     // gD = 0..3
    {
        const float x0 = P.dir[(p0 + ptD) * 3 + 0];
        const float x1 = P.dir[(p0 + ptD) * 3 + 1];
        const float x2 = P.dir[(p0 + ptD) * 3 + 2];
#pragma unroll
        for (int j = 0; j < 8; j++) {
            const int d = gD * 8 + j;
            float val = 0.f;
            if (d < 3) val = (d == 0) ? x0 : (d == 1) ? x1 : x2;
            else if (d < 27) {
                const int e = d - 3, f = e / 6, r = e % 6;
                const float x = (r % 3 == 0) ? x0 : (r % 3 == 1) ? x1 : x2;
                const float xf = x * (float)(1 << f);
                val = (r < 3) ? sinf(xf) : cosf(xf);
            }
            de_v[j] = f2bf(val);
        }
    }

    // hidden/out: 8 waves, each nb = wave (32 n), all 4 m-blocks (128 pts)
    layer32< 4, 8, 4, 0>(P.w + OFF_IN, nullptr, P.b_in, X, P.out, p0, wave, 0, wave, lane);
    layer32<16, 8, 4, 0>(P.w + OFF_H0, nullptr, P.b_h0, X, P.out, p0, wave, 0, wave, lane);
    layer32<16, 8, 4, 0>(P.w + OFF_H1, nullptr, P.b_h1, X, P.out, p0, wave, 0, wave, lane);
    layer32<16, 8, 4, 0>(P.w + OFF_H2, nullptr, P.b_h2, X, P.out, p0, wave, 0, wave, lane);
    layer32<16, 8, 4, 0>(P.w + OFF_H3, nullptr, P.b_h3, X, P.out, p0, wave, 0, wave, lane);
    layer32<20, 8, 4, 0>(P.w + OFF_H4, nullptr, P.b_h4, X, P.out, p0, wave, 0, wave, lane); // concat

    // DE splice into groups 32..35: h4's BAR2 closed all reads of 32..39;
    // h4's epilogue and this splice write disjoint groups; h5's BAR1
    // publishes both. Cols 283..287 are real zeros (de_v zero for d>=27).
    *(bf16x8*)(X + ((size_t)(32 + gD) * 128 + ptD) * 8) = de_v;

    layer32<16, 8, 4, 0>(P.w + OFF_H5, nullptr, P.b_h5, X, P.out, p0, wave, 0, wave, lane);
    layer32<16, 8, 4, 0>(P.w + OFF_H6, nullptr, P.b_h6, X, P.out, p0, wave, 0, wave, lane);
    layer32<16, 8, 4, 1>(P.w + OFF_OUT, P.w + OFF_OUTD, P.b_out, X, P.out, p0, wave, 0, wave, lane);

    // r1 (K=288 -> 128): nb = wave&3, m-half = wave>>2 (2 m-blocks each)
    layer32<18, 4, 2, 0>(P.w + OFF_R1, nullptr, P.b_r1, X, P.out, p0, wave & 3, (wave >> 2) * 2, wave, lane);

    // ---- r2 (128 -> 3) + sigmoid; 16x16, 8 waves, one 16-pt tile each ----
    __syncthreads();
    {
        const int l15 = lane & 15, quad = lane >> 4;
        f32x4 acc = (f32x4){0.f, 0.f, 0.f, 0.f};
        const short* xb = X + quad * 1024 + (wave * 16 + l15) * 8;
#pragma unroll
        for (int kt = 0; kt < 4; ++kt) {
            bf16x8 b = *(const bf16x8*)(xb + kt * 4096);
            bf16x8 a = *(const bf16x8*)(P.w + OFF_R2 + (size_t)(kt * 64 + lane) * 8);
            acc = __builtin_amdgcn_mfma_f32_16x16x32_bf16(a, b, acc, 0, 0, 0);
        }
        if (quad == 0) {                   // rows r = rgb channel
#pragma unroll
            for (int r = 0; r < 3; r++) {
                const float v = acc[r] + P.b_r2[r];
                P.out[(size_t)(p0 + wave * 16 + l15) * 3 + r] = 1.f / (1.f + expf(-v));
            }
        }
    }
}

extern "C" void kernel_launch(void* const* d_in, const int* in_sizes, int n_in,
                              void* d_out, int out_size, void* d_ws, size_t ws_size,
                              hipStream_t stream) {
    short* ws = (short*)d_ws;

    PrepP pp;
    pp.W[0]  = (const float*)d_in[2];   // W_in
    pp.W[1]  = (const float*)d_in[4];   // W_h0
    pp.W[2]  = (const float*)d_in[6];   // W_h1
    pp.W[3]  = (const float*)d_in[8];   // W_h2
    pp.W[4]  = (const float*)d_in[10];  // W_h3
    pp.W[5]  = (const float*)d_in[12];  // W_h4
    pp.W[6]  = (const float*)d_in[14];  // W_h5
    pp.W[7]  = (const float*)d_in[16];  // W_h6
    pp.W[8]  = (const float*)d_in[18];  // W_out
    pp.W[9]  = (const float*)d_in[20];  // W_r1
    pp.W[10] = (const float*)d_in[22];  // W_r2
    pp.ws = ws;
    hipLaunchKernelGGL(prep_all, dim3((WS_TOTAL + 255) / 256), dim3(256), 0, stream, pp);

    Params P;
    P.pos  = (const float*)d_in[0];
    P.dir  = (const float*)d_in[1];
    P.b_in = (const float*)d_in[3];
    P.b_h0 = (const float*)d_in[5];
    P.b_h1 = (const float*)d_in[7];
    P.b_h2 = (const float*)d_in[9];
    P.b_h3 = (const float*)d_in[11];
    P.b_h4 = (const float*)d_in[13];
    P.b_h5 = (const float*)d_in[15];
    P.b_h6 = (const float*)d_in[17];
    P.b_out = (const float*)d_in[19];
    P.b_r1 = (const float*)d_in[21];
    P.b_r2 = (const float*)d_in[23];
    P.w = ws;
    P.out = (float*)d_out;
    hipLaunchKernelGGL(nerf_fused, dim3(NPTS / MT), dim3(512), 0, stream, P);
}